// Round 11
// baseline (142.860 us; speedup 1.0000x reference)
//
#include <hip/hip_runtime.h>

#define S_LEN 4096   // H*W
#define C_CH  256
#define D_CH  128
// softmax scale folded into exp2: lambda = (1/sqrt(256)) * log2(e)  [folded into Q at proj]
#define LAMBDA 0.09016844005555896f

typedef __attribute__((ext_vector_type(8)))  short short8;   // 8 x bf16 (4 VGPR)
typedef __attribute__((ext_vector_type(4)))  float f32x4;
typedef __attribute__((ext_vector_type(16))) float f32x16;

union PFrag { unsigned u[4]; short8 v; };

static __device__ __forceinline__ unsigned short f2bf(float x) {
    union { float f; unsigned u; } v; v.f = x;
    unsigned r = v.u + 0x7FFFu + ((v.u >> 16) & 1u);   // RNE
    return (unsigned short)(r >> 16);
}

static __device__ __forceinline__ void gload_lds16(const void* g, void* l) {
    __builtin_amdgcn_global_load_lds(
        (const __attribute__((address_space(1))) void*)g,
        (__attribute__((address_space(3))) void*)l, 16, 0, 0);
}

// ---------- kernel 1: x f32 -> xb bf16, layout [n][c][s] (V operand) ----------
__global__ void nlm_conv_kernel(const float* __restrict__ x, unsigned short* __restrict__ xb) {
    size_t base = ((size_t)blockIdx.x * 256 + threadIdx.x) * 4;
    float4 v = *reinterpret_cast<const float4*>(x + base);
    ushort4 b; b.x = f2bf(v.x); b.y = f2bf(v.y); b.z = f2bf(v.z); b.w = f2bf(v.w);
    *reinterpret_cast<ushort4*>(xb + base) = b;
}

// ---------- kernel 2: theta_w/phi_w f32 -> bf16, wb = [2][128][256] ----------
__global__ void nlm_wconv_kernel(const float* __restrict__ tw, const float* __restrict__ pw,
                                 unsigned short* __restrict__ wb) {
    int base = (blockIdx.x * 256 + threadIdx.x) * 4;
    const float* src = (base < 32768) ? (tw + base) : (pw + base - 32768);
    float4 v = *reinterpret_cast<const float4*>(src);
    ushort4 b; b.x = f2bf(v.x); b.y = f2bf(v.y); b.z = f2bf(v.z); b.w = f2bf(v.w);
    *reinterpret_cast<ushort4*>(wb + base) = b;
}

// ---------- kernel 3: projections Q[n][s][128] (pre-scaled by lambda), K[n][t][128] ----------
__launch_bounds__(256, 1)
__global__ void nlm_proj_kernel(const float* __restrict__ x,
                                const unsigned short* __restrict__ wb,
                                const float* __restrict__ tb, const float* __restrict__ pbias,
                                unsigned short* __restrict__ Qb, unsigned short* __restrict__ Kb) {
    const int n    = blockIdx.y;
    const int wave = threadIdx.x >> 6;
    const int lane = threadIdx.x & 63;
    const int sl   = lane & 15, g = lane >> 4;
    const int s0   = blockIdx.x * 64 + wave * 16;
    const float* xn = x + (size_t)n * C_CH * S_LEN;

    f32x4 acc[16];
    #pragma unroll
    for (int i = 0; i < 16; ++i) acc[i] = (f32x4){0.f, 0.f, 0.f, 0.f};

    #pragma unroll 1
    for (int cc = 0; cc < 8; ++cc) {
        short8 af;                                   // A[m=s][k=c]: lane m=sl, k=g*8+j
        #pragma unroll
        for (int j = 0; j < 8; ++j) {
            float v = xn[(size_t)(cc * 32 + g * 8 + j) * S_LEN + s0 + sl];
            af[j] = (short)f2bf(v);
        }
        #pragma unroll
        for (int t = 0; t < 16; ++t) {               // 0..7 theta tiles, 8..15 phi tiles
            const unsigned short* wp = wb + (size_t)(t >> 3) * (D_CH * C_CH)
                                          + (size_t)((t & 7) * 16 + sl) * C_CH + cc * 32 + g * 8;
            short8 bf = *reinterpret_cast<const short8*>(wp);
            acc[t] = __builtin_amdgcn_mfma_f32_16x16x32_bf16(af, bf, acc[t], 0, 0, 0);
        }
    }
    unsigned short* Qn = Qb + (size_t)n * S_LEN * D_CH;
    unsigned short* Kn = Kb + (size_t)n * S_LEN * D_CH;
    #pragma unroll
    for (int t = 0; t < 16; ++t) {
        const float bias = (t < 8 ? tb : pbias)[(t & 7) * 16 + sl];
        unsigned short* dst = (t < 8 ? Qn : Kn);
        #pragma unroll
        for (int r = 0; r < 4; ++r) {                // D row = g*4+r, col = sl
            float val = acc[t][r] + bias;
            if (t < 8) val *= LAMBDA;                // fold softmax scale into Q
            dst[(size_t)(s0 + g * 4 + r) * D_CH + (t & 7) * 16 + sl] = f2bf(val);
        }
    }
}

// ---------- kernel 4: flash attention, pipelined 32x32 waves, t-split xTSPLIT ----------
// 128*TSPLIT blocks = 4 n x TSPLIT t-chunks x 32 s-blocks(128 s). 4 waves x 32 q-rows.
// Per iter: ONE barrier; stage K(it+1) [2-buf] + V(it+1) [3-buf]; QK(it) MFMAs;
// PV(it-1) MFMAs (V from LDS, P from regs) interleave with QK on the matrix pipe;
// exp(it) -> P-frags in reg (cvt_pk+permlane32_swap); vmcnt(0) before next barrier.
// launch_bounds(256,2): ~120 arch + 128 acc regs -> 2 blocks/CU when grid=512.
template<int TSPLIT>
__launch_bounds__(256, 2)
__global__ void nlm_attn_kernel(const unsigned short* __restrict__ Qb,
                                const unsigned short* __restrict__ Kb,
                                const unsigned short* __restrict__ xb,
                                float* __restrict__ part0, float* __restrict__ part1,
                                float* __restrict__ part2, float* __restrict__ part3,
                                float* __restrict__ lbuf) {
    constexpr int TRANGE = S_LEN / TSPLIT;
    constexpr int NITv   = TRANGE / 32;
    constexpr int TOTAL  = 128 * TSPLIT;
    // XCD swizzle: TOTAL/8 consecutive newb per XCD.
    const int sid  = blockIdx.x;
    const int newb = (sid & 7) * (TOTAL / 8) + (sid >> 3);
    const int n    = newb / (TOTAL / 4);
    const int th   = (newb >> 5) & (TSPLIT - 1);
    const int sb   = newb & 31;
    const int lane = threadIdx.x & 63;
    const int wave = threadIdx.x >> 6;
    const int l31  = lane & 31;
    const int h    = lane >> 5;
    const int s0   = sb * 128 + wave * 32;           // this wave's 32 q-rows
    const int tbase = th * TRANGE;

    __shared__ unsigned short Klds[2][32 * 128];     // [t-local][d], chunk-XOR swizzled
    __shared__ unsigned short Vlds[3][256 * 32];     // [c][t-local], chunk-XOR swizzled

    const unsigned short* Qn = Qb + (size_t)n * S_LEN * D_CH;
    const unsigned short* Kn = Kb + (size_t)n * S_LEN * D_CH;
    const unsigned short* xn = xb + (size_t)n * C_CH * S_LEN;

    // Q fragments (B operand): lane (s=l31, h): d = ks*16 + h*8 + j
    short8 qf[8];
    #pragma unroll
    for (int ks = 0; ks < 8; ++ks)
        qf[ks] = *reinterpret_cast<const short8*>(Qn + (size_t)(s0 + l31) * D_CH + ks * 16 + h * 8);

    f32x16 oacc[8];                                  // O^T: c-block cb*32.., s = s0+l31
    #pragma unroll
    for (int i = 0; i < 8; ++i)
        #pragma unroll
        for (int r = 0; r < 16; ++r) oacc[i][r] = 0.f;
    float lsum = 0.f;                                // per-lane partial row sum

    auto kstage = [&](int itv, int slot) {           // 32 rows x 256B, 2 insts/wave
        const int it = itv < NITv ? itv : NITv - 1;  // clamp: tail stages dup tile (unread)
        const int t0 = tbase + it * 32;
        #pragma unroll
        for (int i = 0; i < 2; ++i) {
            const int rl = wave * 8 + i * 4 + (lane >> 4);
            const int ch = (lane & 15) ^ (rl & 7);   // LDS[r][q] = G[t0+r][q^(r&7)]
            gload_lds16(Kn + (size_t)(t0 + rl) * D_CH + ch * 8,
                        &Klds[slot][(wave * 8 + i * 4) * 128]);
        }
    };
    auto vstage = [&](int itv, int slot) {           // 256 rows x 64B, 4 insts/wave
        const int it = itv < NITv ? itv : NITv - 1;
        const int t0 = tbase + it * 32;
        #pragma unroll
        for (int i = 0; i < 4; ++i) {
            const int row = wave * 64 + i * 16 + (lane >> 2);
            const int ch = (lane & 3) ^ ((row >> 1) & 3);
            gload_lds16(xn + (size_t)row * S_LEN + t0 + ch * 8,
                        &Vlds[slot][(wave * 64 + i * 16) * 32]);
        }
    };

    // ---- PV step for tile j (V from LDS slot j%3, P-fragments in registers) ----
    auto pv_step = [&](int j, PFrag& pa0, PFrag& pa1) {
        const unsigned short* Vl = &Vlds[j % 3][0];
        #pragma unroll
        for (int cb = 0; cb < 8; ++cb) {
            const int c = cb * 32 + l31;
            const int ch0 = (0 + h) ^ ((c >> 1) & 3);
            const int ch1 = (2 + h) ^ ((c >> 1) & 3);
            short8 vf0 = *reinterpret_cast<const short8*>(&Vl[c * 32 + ch0 * 8]);
            short8 vf1 = *reinterpret_cast<const short8*>(&Vl[c * 32 + ch1 * 8]);
            oacc[cb] = __builtin_amdgcn_mfma_f32_32x32x16_bf16(vf0, pa0.v, oacc[cb], 0, 0, 0);
            oacc[cb] = __builtin_amdgcn_mfma_f32_32x32x16_bf16(vf1, pa1.v, oacc[cb], 0, 0, 0);
        }
    };

    // ---- one pipelined iteration: uses paU (P of it-1), builds paM (P of it) ----
    auto body = [&](int it, PFrag& paU0, PFrag& paU1, PFrag& paM0, PFrag& paM1) {
        __builtin_amdgcn_s_barrier();                // K(it),V(it) landed (vmcnt(0) below)
        __builtin_amdgcn_sched_barrier(0);
        kstage(it + 1, (it + 1) & 1);
        vstage(it + 1, (it + 1) % 3);                // != (it-1)%3 and != it%3: safe

        // ---- QK(it): S^T[t][s] = K_tile * Q^T, 2 accumulator chains ----
        const int kslot = it & 1;
        f32x16 sa, sb2;
        #pragma unroll
        for (int r = 0; r < 16; ++r) { sa[r] = 0.f; sb2[r] = 0.f; }
        #pragma unroll
        for (int ks = 0; ks < 4; ++ks) {             // A: lane (t=l31,h): d=ks*16+h*8+j
            const int ch = (ks * 2 + h) ^ (l31 & 7);
            short8 kf = *reinterpret_cast<const short8*>(&Klds[kslot][l31 * 128 + ch * 8]);
            sa = __builtin_amdgcn_mfma_f32_32x32x16_bf16(kf, qf[ks], sa, 0, 0, 0);
        }
        #pragma unroll
        for (int ks = 4; ks < 8; ++ks) {
            const int ch = (ks * 2 + h) ^ (l31 & 7);
            short8 kf = *reinterpret_cast<const short8*>(&Klds[kslot][l31 * 128 + ch * 8]);
            sb2 = __builtin_amdgcn_mfma_f32_32x32x16_bf16(kf, qf[ks], sb2, 0, 0, 0);
        }

        // ---- PV(it-1): independent of QK -> fills MFMA pipe while QK results land ----
        if (it > 0) pv_step(it - 1, paU0, paU1);

        // ---- exp (no max; lambda pre-folded into Q) ----
        float p[16];
        float rs = 0.f;
        #pragma unroll
        for (int r = 0; r < 16; ++r) {
            p[r] = __builtin_amdgcn_exp2f(sa[r] + sb2[r]);
            rs += p[r];
        }
        lsum += rs;

        // ---- P -> bf16 B-fragments in-register (cvt_pk + permlane32_swap) ----
        unsigned W0, W1, W2, W3, W4, W5, W6, W7;
        asm("v_cvt_pk_bf16_f32 %0, %1, %2" : "=v"(W0) : "v"(p[0]),  "v"(p[1]));
        asm("v_cvt_pk_bf16_f32 %0, %1, %2" : "=v"(W1) : "v"(p[2]),  "v"(p[3]));
        asm("v_cvt_pk_bf16_f32 %0, %1, %2" : "=v"(W2) : "v"(p[4]),  "v"(p[5]));
        asm("v_cvt_pk_bf16_f32 %0, %1, %2" : "=v"(W3) : "v"(p[6]),  "v"(p[7]));
        asm("v_cvt_pk_bf16_f32 %0, %1, %2" : "=v"(W4) : "v"(p[8]),  "v"(p[9]));
        asm("v_cvt_pk_bf16_f32 %0, %1, %2" : "=v"(W5) : "v"(p[10]), "v"(p[11]));
        asm("v_cvt_pk_bf16_f32 %0, %1, %2" : "=v"(W6) : "v"(p[12]), "v"(p[13]));
        asm("v_cvt_pk_bf16_f32 %0, %1, %2" : "=v"(W7) : "v"(p[14]), "v"(p[15]));
        asm("v_permlane32_swap_b32 %0, %1" : "+v"(W0), "+v"(W2));
        asm("v_permlane32_swap_b32 %0, %1" : "+v"(W1), "+v"(W3));
        asm("v_permlane32_swap_b32 %0, %1" : "+v"(W4), "+v"(W6));
        asm("v_permlane32_swap_b32 %0, %1" : "+v"(W5), "+v"(W7));
        paM0.u[0] = W0; paM0.u[1] = W1; paM0.u[2] = W2; paM0.u[3] = W3;
        paM1.u[0] = W4; paM1.u[1] = W5; paM1.u[2] = W6; paM1.u[3] = W7;

        // drain this body's K(it+1)+V(it+1) DMAs -> next barrier guarantees them landed
        asm volatile("s_waitcnt vmcnt(0)" ::: "memory");
        __builtin_amdgcn_sched_barrier(0);
    };

    // prologue: K(0), V(0)
    kstage(0, 0); vstage(0, 0);
    asm volatile("s_waitcnt vmcnt(0)" ::: "memory");

    PFrag paA0, paA1, paB0, paB1;
    paA0.u[0] = paA0.u[1] = paA0.u[2] = paA0.u[3] = 0;
    paA1 = paA0; paB0 = paA0; paB1 = paA0;

    #pragma unroll 1
    for (int io = 0; io < NITv / 2; ++io) {
        body(io * 2,     paA0, paA1, paB0, paB1);
        body(io * 2 + 1, paB0, paB1, paA0, paA1);
    }

    // ---- epilogue: PV(NITv-1) (slot untouched since it landed), reduce lsum, store ----
    pv_step(NITv - 1, paA0, paA1);
    float lt = lsum + __shfl_xor(lsum, 32);          // full row sum for this t-chunk
    float* dst = (th == 0) ? part0 : (th == 1) ? part1 : (th == 2) ? part2 : part3;
    if (lane < 32) lbuf[th * 16384 + n * 4096 + s0 + lane] = lt;
    float* on = dst + (size_t)n * C_CH * S_LEN;
    #pragma unroll
    for (int cb = 0; cb < 8; ++cb) {
        #pragma unroll
        for (int r = 0; r < 16; ++r) {
            const int c = cb * 32 + (r & 3) + 8 * (r >> 2) + 4 * h;
            on[(size_t)c * S_LEN + s0 + l31] = oacc[cb][r];
        }
    }
}

// ---------- kernel 5: combine t-chunks: out = sum(p_i) / sum(l_i) ----------
template<int TSPLIT>
__global__ void nlm_combine_kernel(float* __restrict__ out, const float* __restrict__ p1,
                                   const float* __restrict__ p2, const float* __restrict__ p3,
                                   const float* __restrict__ lbuf) {
    const size_t e0 = ((size_t)blockIdx.x * 256 + threadIdx.x) * 4;
    const int n = (int)(e0 >> 20);
    const int s = (int)(e0 & 4095);
    float4 o = *reinterpret_cast<const float4*>(out + e0);
    float4 l = *reinterpret_cast<const float4*>(lbuf + n * 4096 + s);
    {
        float4 ov = *reinterpret_cast<const float4*>(p1 + e0);
        float4 lv = *reinterpret_cast<const float4*>(lbuf + 16384 + n * 4096 + s);
        o.x += ov.x; o.y += ov.y; o.z += ov.z; o.w += ov.w;
        l.x += lv.x; l.y += lv.y; l.z += lv.z; l.w += lv.w;
    }
    if (TSPLIT == 4) {
        float4 ov = *reinterpret_cast<const float4*>(p2 + e0);
        float4 lv = *reinterpret_cast<const float4*>(lbuf + 2 * 16384 + n * 4096 + s);
        o.x += ov.x; o.y += ov.y; o.z += ov.z; o.w += ov.w;
        l.x += lv.x; l.y += lv.y; l.z += lv.z; l.w += lv.w;
        float4 ow = *reinterpret_cast<const float4*>(p3 + e0);
        float4 lw = *reinterpret_cast<const float4*>(lbuf + 3 * 16384 + n * 4096 + s);
        o.x += ow.x; o.y += ow.y; o.z += ow.z; o.w += ow.w;
        l.x += lw.x; l.y += lw.y; l.z += lw.z; l.w += lw.w;
    }
    float4 r;
    r.x = o.x / l.x; r.y = o.y / l.y; r.z = o.z / l.z; r.w = o.w / l.w;
    *reinterpret_cast<float4*>(out + e0) = r;
}

extern "C" void kernel_launch(void* const* d_in, const int* in_sizes, int n_in,
                              void* d_out, int out_size, void* d_ws, size_t ws_size,
                              hipStream_t stream) {
    const float* x  = (const float*)d_in[0];
    const float* tw = (const float*)d_in[1];
    const float* tb = (const float*)d_in[2];
    const float* pw = (const float*)d_in[3];
    const float* pb = (const float*)d_in[4];
    float* out = (float*)d_out;

    char* ws = (char*)d_ws;
    unsigned short* xb = (unsigned short*)(ws);               //  8,388,608 B
    unsigned short* Qb = (unsigned short*)(ws + 8388608);     //  4,194,304 B
    unsigned short* Kb = (unsigned short*)(ws + 12582912);    //  4,194,304 B
    unsigned short* wb = (unsigned short*)(ws + 16777216);    //    131,072 B
    float*          lb = (float*)(ws + 16908288);             //    262,144 B
    float*          p1 = (float*)(ws + 17825792);             // 16,777,216 B
    float*          p2 = (float*)(ws + 34603008);             // 16,777,216 B
    float*          p3 = (float*)(ws + 51380224);             // 16,777,216 B

    nlm_conv_kernel<<<4096, 256, 0, stream>>>(x, xb);
    nlm_wconv_kernel<<<64, 256, 0, stream>>>(tw, pw, wb);
    nlm_proj_kernel<<<dim3(64, 4), 256, 0, stream>>>(x, wb, tb, pb, Qb, Kb);
    if (ws_size >= (size_t)68157440) {               // 4-way t-split: 512 blocks, 2/CU
        nlm_attn_kernel<4><<<512, 256, 0, stream>>>(Qb, Kb, xb, out, p1, p2, p3, lb);
        nlm_combine_kernel<4><<<4096, 256, 0, stream>>>(out, p1, p2, p3, lb);
    } else {                                          // fallback: 2-way t-split
        nlm_attn_kernel<2><<<256, 256, 0, stream>>>(Qb, Kb, xb, out, p1, p1, p1, lb);
        nlm_combine_kernel<2><<<4096, 256, 0, stream>>>(out, p1, p1, p1, lb);
    }
}

// Round 12
// 111.426 us; speedup vs baseline: 1.2821x; 1.2821x over previous
//
#include <hip/hip_runtime.h>

#define S_LEN 4096   // H*W
#define C_CH  256
#define D_CH  128
// softmax scale folded into exp2: lambda = (1/sqrt(256)) * log2(e)  [folded into Q at proj]
#define LAMBDA 0.09016844005555896f

typedef __attribute__((ext_vector_type(8)))  short short8;   // 8 x bf16 (4 VGPR)
typedef __attribute__((ext_vector_type(4)))  float f32x4;
typedef __attribute__((ext_vector_type(16))) float f32x16;

union PFrag { unsigned u[4]; short8 v; };

static __device__ __forceinline__ unsigned short f2bf(float x) {
    union { float f; unsigned u; } v; v.f = x;
    unsigned r = v.u + 0x7FFFu + ((v.u >> 16) & 1u);   // RNE
    return (unsigned short)(r >> 16);
}

static __device__ __forceinline__ void gload_lds16(const void* g, void* l) {
    __builtin_amdgcn_global_load_lds(
        (const __attribute__((address_space(1))) void*)g,
        (__attribute__((address_space(3))) void*)l, 16, 0, 0);
}

// ---------- kernel 1: x f32 -> xb bf16, layout [n][c][s] (V operand) ----------
__global__ void nlm_conv_kernel(const float* __restrict__ x, unsigned short* __restrict__ xb) {
    size_t base = ((size_t)blockIdx.x * 256 + threadIdx.x) * 4;
    float4 v = *reinterpret_cast<const float4*>(x + base);
    ushort4 b; b.x = f2bf(v.x); b.y = f2bf(v.y); b.z = f2bf(v.z); b.w = f2bf(v.w);
    *reinterpret_cast<ushort4*>(xb + base) = b;
}

// ---------- kernel 2: theta_w/phi_w f32 -> bf16, wb = [2][128][256] ----------
__global__ void nlm_wconv_kernel(const float* __restrict__ tw, const float* __restrict__ pw,
                                 unsigned short* __restrict__ wb) {
    int base = (blockIdx.x * 256 + threadIdx.x) * 4;
    const float* src = (base < 32768) ? (tw + base) : (pw + base - 32768);
    float4 v = *reinterpret_cast<const float4*>(src);
    ushort4 b; b.x = f2bf(v.x); b.y = f2bf(v.y); b.z = f2bf(v.z); b.w = f2bf(v.w);
    *reinterpret_cast<ushort4*>(wb + base) = b;
}

// ---------- kernel 3: projections Q[n][s][128] (pre-scaled by lambda), K[n][t][128] ----------
__launch_bounds__(256, 1)
__global__ void nlm_proj_kernel(const float* __restrict__ x,
                                const unsigned short* __restrict__ wb,
                                const float* __restrict__ tb, const float* __restrict__ pbias,
                                unsigned short* __restrict__ Qb, unsigned short* __restrict__ Kb) {
    const int n    = blockIdx.y;
    const int wave = threadIdx.x >> 6;
    const int lane = threadIdx.x & 63;
    const int sl   = lane & 15, g = lane >> 4;
    const int s0   = blockIdx.x * 64 + wave * 16;
    const float* xn = x + (size_t)n * C_CH * S_LEN;

    f32x4 acc[16];
    #pragma unroll
    for (int i = 0; i < 16; ++i) acc[i] = (f32x4){0.f, 0.f, 0.f, 0.f};

    #pragma unroll 1
    for (int cc = 0; cc < 8; ++cc) {
        short8 af;                                   // A[m=s][k=c]: lane m=sl, k=g*8+j
        #pragma unroll
        for (int j = 0; j < 8; ++j) {
            float v = xn[(size_t)(cc * 32 + g * 8 + j) * S_LEN + s0 + sl];
            af[j] = (short)f2bf(v);
        }
        #pragma unroll
        for (int t = 0; t < 16; ++t) {               // 0..7 theta tiles, 8..15 phi tiles
            const unsigned short* wp = wb + (size_t)(t >> 3) * (D_CH * C_CH)
                                          + (size_t)((t & 7) * 16 + sl) * C_CH + cc * 32 + g * 8;
            short8 bf = *reinterpret_cast<const short8*>(wp);
            acc[t] = __builtin_amdgcn_mfma_f32_16x16x32_bf16(af, bf, acc[t], 0, 0, 0);
        }
    }
    unsigned short* Qn = Qb + (size_t)n * S_LEN * D_CH;
    unsigned short* Kn = Kb + (size_t)n * S_LEN * D_CH;
    #pragma unroll
    for (int t = 0; t < 16; ++t) {
        const float bias = (t < 8 ? tb : pbias)[(t & 7) * 16 + sl];
        unsigned short* dst = (t < 8 ? Qn : Kn);
        #pragma unroll
        for (int r = 0; r < 4; ++r) {                // D row = g*4+r, col = sl
            float val = acc[t][r] + bias;
            if (t < 8) val *= LAMBDA;                // fold softmax scale into Q
            dst[(size_t)(s0 + g * 4 + r) * D_CH + (t & 7) * 16 + sl] = f2bf(val);
        }
    }
}

// ---------- kernel 4: flash attention, 8-wave blocks, shared staging, t-split ----------
// 64*TSPLIT blocks (TSPLIT=4 -> 256 = 1/CU, 2 waves/SIMD). Block = 8 waves x 32 q-rows
// = 256 s. Per body: ONE barrier; per-wave staging (1 K-inst + 2 V-insts); QK(it)
// 2x4-chain; PV(it-1) from LDS V + reg P; exp; cvt_pk+permlane P; vmcnt(0).
// K 2-buf, V 3-buf, 64KB LDS. launch_bounds(512,2): 256-reg budget (proven fit, r11).
template<int TSPLIT>
__launch_bounds__(512, 2)
__global__ void nlm_attn_kernel(const unsigned short* __restrict__ Qb,
                                const unsigned short* __restrict__ Kb,
                                const unsigned short* __restrict__ xb,
                                float* __restrict__ part0, float* __restrict__ part1,
                                float* __restrict__ part2, float* __restrict__ part3,
                                float* __restrict__ lbuf) {
    constexpr int TRANGE = S_LEN / TSPLIT;
    constexpr int NITv   = TRANGE / 32;
    constexpr int TOTAL  = 64 * TSPLIT;
    // XCD swizzle: TOTAL/8 consecutive newb per XCD.
    const int sid  = blockIdx.x;
    const int newb = (sid & 7) * (TOTAL / 8) + (sid >> 3);
    const int n    = newb / (16 * TSPLIT);
    const int th   = (newb >> 4) & (TSPLIT - 1);
    const int sb   = newb & 15;
    const int lane = threadIdx.x & 63;
    const int wave = threadIdx.x >> 6;               // 0..7
    const int l31  = lane & 31;
    const int h    = lane >> 5;
    const int s0   = sb * 256 + wave * 32;           // this wave's 32 q-rows
    const int tbase = th * TRANGE;

    __shared__ unsigned short Klds[2][32 * 128];     // [t-local][d], chunk-XOR swizzled
    __shared__ unsigned short Vlds[3][256 * 32];     // [c][t-local], chunk-XOR swizzled

    const unsigned short* Qn = Qb + (size_t)n * S_LEN * D_CH;
    const unsigned short* Kn = Kb + (size_t)n * S_LEN * D_CH;
    const unsigned short* xn = xb + (size_t)n * C_CH * S_LEN;

    // Q fragments (B operand): lane (s=l31, h): d = ks*16 + h*8 + j
    short8 qf[8];
    #pragma unroll
    for (int ks = 0; ks < 8; ++ks)
        qf[ks] = *reinterpret_cast<const short8*>(Qn + (size_t)(s0 + l31) * D_CH + ks * 16 + h * 8);

    f32x16 oacc[8];                                  // O^T: c-block cb*32.., s = s0+l31
    #pragma unroll
    for (int i = 0; i < 8; ++i)
        #pragma unroll
        for (int r = 0; r < 16; ++r) oacc[i][r] = 0.f;
    float lsum = 0.f;                                // per-lane partial row sum

    auto kstage = [&](int itv, int slot) {           // 32 rows x 256B, 1 inst/wave
        const int it = itv < NITv ? itv : NITv - 1;  // clamp: tail stages dup tile (unread)
        const int t0 = tbase + it * 32;
        const int rl = wave * 4 + (lane >> 4);
        const int ch = (lane & 15) ^ (rl & 7);       // LDS[r][q] = G[t0+r][q^(r&7)]
        gload_lds16(Kn + (size_t)(t0 + rl) * D_CH + ch * 8,
                    &Klds[slot][(wave * 4) * 128]);
    };
    auto vstage = [&](int itv, int slot) {           // 256 rows x 64B, 2 insts/wave
        const int it = itv < NITv ? itv : NITv - 1;
        const int t0 = tbase + it * 32;
        #pragma unroll
        for (int i = 0; i < 2; ++i) {
            const int row = wave * 32 + i * 16 + (lane >> 2);
            const int ch = (lane & 3) ^ ((row >> 1) & 3);
            gload_lds16(xn + (size_t)row * S_LEN + t0 + ch * 8,
                        &Vlds[slot][(wave * 32 + i * 16) * 32]);
        }
    };

    // ---- PV step for tile j (V from LDS slot j%3, P-fragments in registers) ----
    auto pv_step = [&](int j, PFrag& pa0, PFrag& pa1) {
        const unsigned short* Vl = &Vlds[j % 3][0];
        #pragma unroll
        for (int cb = 0; cb < 8; ++cb) {
            const int c = cb * 32 + l31;
            const int ch0 = (0 + h) ^ ((c >> 1) & 3);
            const int ch1 = (2 + h) ^ ((c >> 1) & 3);
            short8 vf0 = *reinterpret_cast<const short8*>(&Vl[c * 32 + ch0 * 8]);
            short8 vf1 = *reinterpret_cast<const short8*>(&Vl[c * 32 + ch1 * 8]);
            oacc[cb] = __builtin_amdgcn_mfma_f32_32x32x16_bf16(vf0, pa0.v, oacc[cb], 0, 0, 0);
            oacc[cb] = __builtin_amdgcn_mfma_f32_32x32x16_bf16(vf1, pa1.v, oacc[cb], 0, 0, 0);
        }
    };

    // ---- one pipelined iteration: uses paU (P of it-1), builds paM (P of it) ----
    auto body = [&](int it, PFrag& paU0, PFrag& paU1, PFrag& paM0, PFrag& paM1) {
        __builtin_amdgcn_s_barrier();                // K(it),V(it) landed (vmcnt(0) below)
        __builtin_amdgcn_sched_barrier(0);
        kstage(it + 1, (it + 1) & 1);
        vstage(it + 1, (it + 1) % 3);                // != (it-1)%3 and != it%3: safe

        // ---- QK(it): S^T[t][s] = K_tile * Q^T, 2 accumulator chains ----
        const int kslot = it & 1;
        f32x16 sa, sb2;
        #pragma unroll
        for (int r = 0; r < 16; ++r) { sa[r] = 0.f; sb2[r] = 0.f; }
        #pragma unroll
        for (int ks = 0; ks < 4; ++ks) {             // A: lane (t=l31,h): d=ks*16+h*8+j
            const int ch = (ks * 2 + h) ^ (l31 & 7);
            short8 kf = *reinterpret_cast<const short8*>(&Klds[kslot][l31 * 128 + ch * 8]);
            sa = __builtin_amdgcn_mfma_f32_32x32x16_bf16(kf, qf[ks], sa, 0, 0, 0);
        }
        #pragma unroll
        for (int ks = 4; ks < 8; ++ks) {
            const int ch = (ks * 2 + h) ^ (l31 & 7);
            short8 kf = *reinterpret_cast<const short8*>(&Klds[kslot][l31 * 128 + ch * 8]);
            sb2 = __builtin_amdgcn_mfma_f32_32x32x16_bf16(kf, qf[ks], sb2, 0, 0, 0);
        }

        // ---- PV(it-1): independent of QK -> fills MFMA pipe while QK results land ----
        if (it > 0) pv_step(it - 1, paU0, paU1);

        // ---- exp (no max; lambda pre-folded into Q) ----
        float p[16];
        float rs = 0.f;
        #pragma unroll
        for (int r = 0; r < 16; ++r) {
            p[r] = __builtin_amdgcn_exp2f(sa[r] + sb2[r]);
            rs += p[r];
        }
        lsum += rs;

        // ---- P -> bf16 B-fragments in-register (cvt_pk + permlane32_swap) ----
        unsigned W0, W1, W2, W3, W4, W5, W6, W7;
        asm("v_cvt_pk_bf16_f32 %0, %1, %2" : "=v"(W0) : "v"(p[0]),  "v"(p[1]));
        asm("v_cvt_pk_bf16_f32 %0, %1, %2" : "=v"(W1) : "v"(p[2]),  "v"(p[3]));
        asm("v_cvt_pk_bf16_f32 %0, %1, %2" : "=v"(W2) : "v"(p[4]),  "v"(p[5]));
        asm("v_cvt_pk_bf16_f32 %0, %1, %2" : "=v"(W3) : "v"(p[6]),  "v"(p[7]));
        asm("v_cvt_pk_bf16_f32 %0, %1, %2" : "=v"(W4) : "v"(p[8]),  "v"(p[9]));
        asm("v_cvt_pk_bf16_f32 %0, %1, %2" : "=v"(W5) : "v"(p[10]), "v"(p[11]));
        asm("v_cvt_pk_bf16_f32 %0, %1, %2" : "=v"(W6) : "v"(p[12]), "v"(p[13]));
        asm("v_cvt_pk_bf16_f32 %0, %1, %2" : "=v"(W7) : "v"(p[14]), "v"(p[15]));
        asm("v_permlane32_swap_b32 %0, %1" : "+v"(W0), "+v"(W2));
        asm("v_permlane32_swap_b32 %0, %1" : "+v"(W1), "+v"(W3));
        asm("v_permlane32_swap_b32 %0, %1" : "+v"(W4), "+v"(W6));
        asm("v_permlane32_swap_b32 %0, %1" : "+v"(W5), "+v"(W7));
        paM0.u[0] = W0; paM0.u[1] = W1; paM0.u[2] = W2; paM0.u[3] = W3;
        paM1.u[0] = W4; paM1.u[1] = W5; paM1.u[2] = W6; paM1.u[3] = W7;

        // drain this body's K(it+1)+V(it+1) DMAs -> next barrier guarantees them landed
        asm volatile("s_waitcnt vmcnt(0)" ::: "memory");
        __builtin_amdgcn_sched_barrier(0);
    };

    // prologue: K(0), V(0)
    kstage(0, 0); vstage(0, 0);
    asm volatile("s_waitcnt vmcnt(0)" ::: "memory");

    PFrag paA0, paA1, paB0, paB1;
    paA0.u[0] = paA0.u[1] = paA0.u[2] = paA0.u[3] = 0;
    paA1 = paA0; paB0 = paA0; paB1 = paA0;

    #pragma unroll 1
    for (int io = 0; io < NITv / 2; ++io) {
        body(io * 2,     paA0, paA1, paB0, paB1);
        body(io * 2 + 1, paB0, paB1, paA0, paA1);
    }

    // ---- epilogue: PV(NITv-1) (slot untouched since it landed), reduce lsum, store ----
    pv_step(NITv - 1, paA0, paA1);
    float lt = lsum + __shfl_xor(lsum, 32);          // full row sum for this t-chunk
    float* dst = (th == 0) ? part0 : (th == 1) ? part1 : (th == 2) ? part2 : part3;
    if (lane < 32) lbuf[th * 16384 + n * 4096 + s0 + lane] = lt;
    float* on = dst + (size_t)n * C_CH * S_LEN;
    #pragma unroll
    for (int cb = 0; cb < 8; ++cb) {
        #pragma unroll
        for (int r = 0; r < 16; ++r) {
            const int c = cb * 32 + (r & 3) + 8 * (r >> 2) + 4 * h;
            on[(size_t)c * S_LEN + s0 + l31] = oacc[cb][r];
        }
    }
}

// ---------- kernel 5: combine t-chunks: out = sum(p_i) / sum(l_i) ----------
template<int TSPLIT>
__global__ void nlm_combine_kernel(float* __restrict__ out, const float* __restrict__ p1,
                                   const float* __restrict__ p2, const float* __restrict__ p3,
                                   const float* __restrict__ lbuf) {
    const size_t e0 = ((size_t)blockIdx.x * 256 + threadIdx.x) * 4;
    const int n = (int)(e0 >> 20);
    const int s = (int)(e0 & 4095);
    float4 o = *reinterpret_cast<const float4*>(out + e0);
    float4 l = *reinterpret_cast<const float4*>(lbuf + n * 4096 + s);
    {
        float4 ov = *reinterpret_cast<const float4*>(p1 + e0);
        float4 lv = *reinterpret_cast<const float4*>(lbuf + 16384 + n * 4096 + s);
        o.x += ov.x; o.y += ov.y; o.z += ov.z; o.w += ov.w;
        l.x += lv.x; l.y += lv.y; l.z += lv.z; l.w += lv.w;
    }
    if (TSPLIT == 4) {
        float4 ov = *reinterpret_cast<const float4*>(p2 + e0);
        float4 lv = *reinterpret_cast<const float4*>(lbuf + 2 * 16384 + n * 4096 + s);
        o.x += ov.x; o.y += ov.y; o.z += ov.z; o.w += ov.w;
        l.x += lv.x; l.y += lv.y; l.z += lv.z; l.w += lv.w;
        float4 ow = *reinterpret_cast<const float4*>(p3 + e0);
        float4 lw = *reinterpret_cast<const float4*>(lbuf + 3 * 16384 + n * 4096 + s);
        o.x += ow.x; o.y += ow.y; o.z += ow.z; o.w += ow.w;
        l.x += lw.x; l.y += lw.y; l.z += lw.z; l.w += lw.w;
    }
    float4 r;
    r.x = o.x / l.x; r.y = o.y / l.y; r.z = o.z / l.z; r.w = o.w / l.w;
    *reinterpret_cast<float4*>(out + e0) = r;
}

extern "C" void kernel_launch(void* const* d_in, const int* in_sizes, int n_in,
                              void* d_out, int out_size, void* d_ws, size_t ws_size,
                              hipStream_t stream) {
    const float* x  = (const float*)d_in[0];
    const float* tw = (const float*)d_in[1];
    const float* tb = (const float*)d_in[2];
    const float* pw = (const float*)d_in[3];
    const float* pb = (const float*)d_in[4];
    float* out = (float*)d_out;

    char* ws = (char*)d_ws;
    unsigned short* xb = (unsigned short*)(ws);               //  8,388,608 B
    unsigned short* Qb = (unsigned short*)(ws + 8388608);     //  4,194,304 B
    unsigned short* Kb = (unsigned short*)(ws + 12582912);    //  4,194,304 B
    unsigned short* wb = (unsigned short*)(ws + 16777216);    //    131,072 B
    float*          lb = (float*)(ws + 16908288);             //    262,144 B
    float*          p1 = (float*)(ws + 17825792);             // 16,777,216 B
    float*          p2 = (float*)(ws + 34603008);             // 16,777,216 B
    float*          p3 = (float*)(ws + 51380224);             // 16,777,216 B

    nlm_conv_kernel<<<4096, 256, 0, stream>>>(x, xb);
    nlm_wconv_kernel<<<64, 256, 0, stream>>>(tw, pw, wb);
    nlm_proj_kernel<<<dim3(64, 4), 256, 0, stream>>>(x, wb, tb, pb, Qb, Kb);
    if (ws_size >= (size_t)68157440) {               // 4-way t-split: 256 blocks, 8 waves
        nlm_attn_kernel<4><<<256, 512, 0, stream>>>(Qb, Kb, xb, out, p1, p2, p3, lb);
        nlm_combine_kernel<4><<<4096, 256, 0, stream>>>(out, p1, p2, p3, lb);
    } else {                                          // fallback: 2-way t-split
        nlm_attn_kernel<2><<<128, 512, 0, stream>>>(Qb, Kb, xb, out, p1, p1, p1, lb);
        nlm_combine_kernel<2><<<4096, 256, 0, stream>>>(out, p1, p1, p1, lb);
    }
}

// Round 13
// 100.726 us; speedup vs baseline: 1.4183x; 1.1062x over previous
//
#include <hip/hip_runtime.h>

#define S_LEN 4096   // H*W
#define C_CH  256
#define D_CH  128
// softmax scale folded into exp2: lambda = (1/sqrt(256)) * log2(e)  [folded into Q at proj]
#define LAMBDA 0.09016844005555896f

typedef __attribute__((ext_vector_type(8)))  short short8;   // 8 x bf16 (4 VGPR)
typedef __attribute__((ext_vector_type(4)))  float f32x4;
typedef __attribute__((ext_vector_type(16))) float f32x16;

union PFrag { unsigned u[4]; short8 v; };

static __device__ __forceinline__ unsigned short f2bf(float x) {
    union { float f; unsigned u; } v; v.f = x;
    unsigned r = v.u + 0x7FFFu + ((v.u >> 16) & 1u);   // RNE
    return (unsigned short)(r >> 16);
}

static __device__ __forceinline__ void gload_lds16(const void* g, void* l) {
    __builtin_amdgcn_global_load_lds(
        (const __attribute__((address_space(1))) void*)g,
        (__attribute__((address_space(3))) void*)l, 16, 0, 0);
}

// ---------- kernel 1: x f32 -> xb bf16, layout [n][c][s] (V operand) ----------
__global__ void nlm_conv_kernel(const float* __restrict__ x, unsigned short* __restrict__ xb) {
    size_t base = ((size_t)blockIdx.x * 256 + threadIdx.x) * 4;
    float4 v = *reinterpret_cast<const float4*>(x + base);
    ushort4 b; b.x = f2bf(v.x); b.y = f2bf(v.y); b.z = f2bf(v.z); b.w = f2bf(v.w);
    *reinterpret_cast<ushort4*>(xb + base) = b;
}

// ---------- kernel 2: theta_w/phi_w f32 -> bf16, wb = [2][128][256] ----------
__global__ void nlm_wconv_kernel(const float* __restrict__ tw, const float* __restrict__ pw,
                                 unsigned short* __restrict__ wb) {
    int base = (blockIdx.x * 256 + threadIdx.x) * 4;
    const float* src = (base < 32768) ? (tw + base) : (pw + base - 32768);
    float4 v = *reinterpret_cast<const float4*>(src);
    ushort4 b; b.x = f2bf(v.x); b.y = f2bf(v.y); b.z = f2bf(v.z); b.w = f2bf(v.w);
    *reinterpret_cast<ushort4*>(wb + base) = b;
}

// ---------- kernel 3: projections Q[n][s][128] (pre-scaled by lambda), K[n][t][128] ----------
__launch_bounds__(256, 1)
__global__ void nlm_proj_kernel(const float* __restrict__ x,
                                const unsigned short* __restrict__ wb,
                                const float* __restrict__ tb, const float* __restrict__ pbias,
                                unsigned short* __restrict__ Qb, unsigned short* __restrict__ Kb) {
    const int n    = blockIdx.y;
    const int wave = threadIdx.x >> 6;
    const int lane = threadIdx.x & 63;
    const int sl   = lane & 15, g = lane >> 4;
    const int s0   = blockIdx.x * 64 + wave * 16;
    const float* xn = x + (size_t)n * C_CH * S_LEN;

    f32x4 acc[16];
    #pragma unroll
    for (int i = 0; i < 16; ++i) acc[i] = (f32x4){0.f, 0.f, 0.f, 0.f};

    #pragma unroll 1
    for (int cc = 0; cc < 8; ++cc) {
        short8 af;                                   // A[m=s][k=c]: lane m=sl, k=g*8+j
        #pragma unroll
        for (int j = 0; j < 8; ++j) {
            float v = xn[(size_t)(cc * 32 + g * 8 + j) * S_LEN + s0 + sl];
            af[j] = (short)f2bf(v);
        }
        #pragma unroll
        for (int t = 0; t < 16; ++t) {               // 0..7 theta tiles, 8..15 phi tiles
            const unsigned short* wp = wb + (size_t)(t >> 3) * (D_CH * C_CH)
                                          + (size_t)((t & 7) * 16 + sl) * C_CH + cc * 32 + g * 8;
            short8 bf = *reinterpret_cast<const short8*>(wp);
            acc[t] = __builtin_amdgcn_mfma_f32_16x16x32_bf16(af, bf, acc[t], 0, 0, 0);
        }
    }
    unsigned short* Qn = Qb + (size_t)n * S_LEN * D_CH;
    unsigned short* Kn = Kb + (size_t)n * S_LEN * D_CH;
    #pragma unroll
    for (int t = 0; t < 16; ++t) {
        const float bias = (t < 8 ? tb : pbias)[(t & 7) * 16 + sl];
        unsigned short* dst = (t < 8 ? Qn : Kn);
        #pragma unroll
        for (int r = 0; r < 4; ++r) {                // D row = g*4+r, col = sl
            float val = acc[t][r] + bias;
            if (t < 8) val *= LAMBDA;                // fold softmax scale into Q
            dst[(size_t)(s0 + g * 4 + r) * D_CH + (t & 7) * 16 + sl] = f2bf(val);
        }
    }
}

// ---------- kernel 4: flash attention, 8-wave blocks, BT=64, t-split ----------
// 64*TSPLIT blocks (TSPLIT=4 -> 256 = 1/CU, 2 waves/SIMD). Block = 8 waves x 32 q-rows
// = 256 s; BT=64 (16 bodies). Per body: ONE barrier; per-wave staging (2 K + 4 V insts);
// QK 2 chains of 8 (t-low/t-high); exp; cvt_pk+permlane -> 4 P-frags; PV 32 MFMA
// same-body; vmcnt(0). K 2-buf + V 2-buf = 96 KB LDS. ~240 regs under (512,2) budget.
template<int TSPLIT>
__launch_bounds__(512, 2)
__global__ void nlm_attn_kernel(const unsigned short* __restrict__ Qb,
                                const unsigned short* __restrict__ Kb,
                                const unsigned short* __restrict__ xb,
                                float* __restrict__ part0, float* __restrict__ part1,
                                float* __restrict__ part2, float* __restrict__ part3,
                                float* __restrict__ lbuf) {
    constexpr int TRANGE = S_LEN / TSPLIT;
    constexpr int NITv   = TRANGE / 64;
    constexpr int TOTAL  = 64 * TSPLIT;
    // XCD swizzle: TOTAL/8 consecutive newb per XCD.
    const int sid  = blockIdx.x;
    const int newb = (sid & 7) * (TOTAL / 8) + (sid >> 3);
    const int n    = newb / (16 * TSPLIT);
    const int th   = (newb >> 4) & (TSPLIT - 1);
    const int sb   = newb & 15;
    const int lane = threadIdx.x & 63;
    const int wave = threadIdx.x >> 6;               // 0..7
    const int l31  = lane & 31;
    const int h    = lane >> 5;
    const int s0   = sb * 256 + wave * 32;           // this wave's 32 q-rows
    const int tbase = th * TRANGE;

    __shared__ unsigned short Klds[2][64 * 128];     // [t-local][d], chunk-XOR swizzled
    __shared__ unsigned short Vlds[2][256 * 64];     // [c][t-local], chunk-XOR swizzled

    const unsigned short* Qn = Qb + (size_t)n * S_LEN * D_CH;
    const unsigned short* Kn = Kb + (size_t)n * S_LEN * D_CH;
    const unsigned short* xn = xb + (size_t)n * C_CH * S_LEN;

    // Q fragments (B operand): lane (s=l31, h): d = ks*16 + h*8 + j
    short8 qf[8];
    #pragma unroll
    for (int ks = 0; ks < 8; ++ks)
        qf[ks] = *reinterpret_cast<const short8*>(Qn + (size_t)(s0 + l31) * D_CH + ks * 16 + h * 8);

    f32x16 oacc[8];                                  // O^T: c-block cb*32.., s = s0+l31
    #pragma unroll
    for (int i = 0; i < 8; ++i)
        #pragma unroll
        for (int r = 0; r < 16; ++r) oacc[i][r] = 0.f;
    float lsum = 0.f;                                // per-lane partial row sum

    auto kstage = [&](int itv, int slot) {           // 64 rows x 256B, 2 insts/wave
        const int it = itv < NITv ? itv : NITv - 1;  // clamp: tail stages dup tile (unread)
        const int t0 = tbase + it * 64;
        #pragma unroll
        for (int i = 0; i < 2; ++i) {
            const int rl = wave * 8 + i * 4 + (lane >> 4);
            const int ch = (lane & 15) ^ (rl & 7);   // LDS[r][q] = G[t0+r][q^(r&7)]
            gload_lds16(Kn + (size_t)(t0 + rl) * D_CH + ch * 8,
                        &Klds[slot][(wave * 8 + i * 4) * 128]);
        }
    };
    auto vstage = [&](int itv, int slot) {           // 256 rows x 128B, 4 insts/wave
        const int it = itv < NITv ? itv : NITv - 1;
        const int t0 = tbase + it * 64;
        #pragma unroll
        for (int i = 0; i < 4; ++i) {
            const int row = wave * 32 + i * 8 + (lane >> 3);
            const int ch = (lane & 7) ^ (row & 7);   // LDS[c][q] = G[c][q^(c&7)]
            gload_lds16(xn + (size_t)row * S_LEN + t0 + ch * 8,
                        &Vlds[slot][(wave * 32 + i * 8) * 64]);
        }
    };

    // prologue: K(0), V(0)
    kstage(0, 0); vstage(0, 0);
    asm volatile("s_waitcnt vmcnt(0)" ::: "memory");

    #pragma unroll 1
    for (int it = 0; it < NITv; ++it) {
        const int cur = it & 1;
        __builtin_amdgcn_s_barrier();                // K(it),V(it) landed; buf cur^1 free
        __builtin_amdgcn_sched_barrier(0);
        kstage(it + 1, cur ^ 1);
        vstage(it + 1, cur ^ 1);

        // ---- QK(it): S^T = K_tile(64t x 128d) * Q^T(128d x 32s), 2 output chains ----
        f32x16 sa, sb2;                              // t 0..31 / t 32..63
        #pragma unroll
        for (int r = 0; r < 16; ++r) { sa[r] = 0.f; sb2[r] = 0.f; }
        __builtin_amdgcn_s_setprio(1);
        #pragma unroll
        for (int ks = 0; ks < 8; ++ks) {             // A: lane (t,h): d=ks*16+h*8+j
            const int ch = (ks * 2 + h) ^ (l31 & 7);
            short8 kflo = *reinterpret_cast<const short8*>(&Klds[cur][l31 * 128 + ch * 8]);
            short8 kfhi = *reinterpret_cast<const short8*>(&Klds[cur][(32 + l31) * 128 + ch * 8]);
            sa  = __builtin_amdgcn_mfma_f32_32x32x16_bf16(kflo, qf[ks], sa,  0, 0, 0);
            sb2 = __builtin_amdgcn_mfma_f32_32x32x16_bf16(kfhi, qf[ks], sb2, 0, 0, 0);
        }
        __builtin_amdgcn_s_setprio(0);

        // ---- exp (no max; lambda pre-folded) + P-frags (cvt_pk + permlane32_swap) ----
        PFrag pa0, pa1, pa2, pa3;
        float rs = 0.f;
        {
            float p[16];
            #pragma unroll
            for (int r = 0; r < 16; ++r) { p[r] = __builtin_amdgcn_exp2f(sa[r]); rs += p[r]; }
            unsigned W0, W1, W2, W3, W4, W5, W6, W7;
            asm("v_cvt_pk_bf16_f32 %0, %1, %2" : "=v"(W0) : "v"(p[0]),  "v"(p[1]));
            asm("v_cvt_pk_bf16_f32 %0, %1, %2" : "=v"(W1) : "v"(p[2]),  "v"(p[3]));
            asm("v_cvt_pk_bf16_f32 %0, %1, %2" : "=v"(W2) : "v"(p[4]),  "v"(p[5]));
            asm("v_cvt_pk_bf16_f32 %0, %1, %2" : "=v"(W3) : "v"(p[6]),  "v"(p[7]));
            asm("v_cvt_pk_bf16_f32 %0, %1, %2" : "=v"(W4) : "v"(p[8]),  "v"(p[9]));
            asm("v_cvt_pk_bf16_f32 %0, %1, %2" : "=v"(W5) : "v"(p[10]), "v"(p[11]));
            asm("v_cvt_pk_bf16_f32 %0, %1, %2" : "=v"(W6) : "v"(p[12]), "v"(p[13]));
            asm("v_cvt_pk_bf16_f32 %0, %1, %2" : "=v"(W7) : "v"(p[14]), "v"(p[15]));
            asm("v_permlane32_swap_b32 %0, %1" : "+v"(W0), "+v"(W2));
            asm("v_permlane32_swap_b32 %0, %1" : "+v"(W1), "+v"(W3));
            asm("v_permlane32_swap_b32 %0, %1" : "+v"(W4), "+v"(W6));
            asm("v_permlane32_swap_b32 %0, %1" : "+v"(W5), "+v"(W7));
            pa0.u[0] = W0; pa0.u[1] = W1; pa0.u[2] = W2; pa0.u[3] = W3;
            pa1.u[0] = W4; pa1.u[1] = W5; pa1.u[2] = W6; pa1.u[3] = W7;
        }
        {
            float p[16];
            #pragma unroll
            for (int r = 0; r < 16; ++r) { p[r] = __builtin_amdgcn_exp2f(sb2[r]); rs += p[r]; }
            unsigned W0, W1, W2, W3, W4, W5, W6, W7;
            asm("v_cvt_pk_bf16_f32 %0, %1, %2" : "=v"(W0) : "v"(p[0]),  "v"(p[1]));
            asm("v_cvt_pk_bf16_f32 %0, %1, %2" : "=v"(W1) : "v"(p[2]),  "v"(p[3]));
            asm("v_cvt_pk_bf16_f32 %0, %1, %2" : "=v"(W2) : "v"(p[4]),  "v"(p[5]));
            asm("v_cvt_pk_bf16_f32 %0, %1, %2" : "=v"(W3) : "v"(p[6]),  "v"(p[7]));
            asm("v_cvt_pk_bf16_f32 %0, %1, %2" : "=v"(W4) : "v"(p[8]),  "v"(p[9]));
            asm("v_cvt_pk_bf16_f32 %0, %1, %2" : "=v"(W5) : "v"(p[10]), "v"(p[11]));
            asm("v_cvt_pk_bf16_f32 %0, %1, %2" : "=v"(W6) : "v"(p[12]), "v"(p[13]));
            asm("v_cvt_pk_bf16_f32 %0, %1, %2" : "=v"(W7) : "v"(p[14]), "v"(p[15]));
            asm("v_permlane32_swap_b32 %0, %1" : "+v"(W0), "+v"(W2));
            asm("v_permlane32_swap_b32 %0, %1" : "+v"(W1), "+v"(W3));
            asm("v_permlane32_swap_b32 %0, %1" : "+v"(W4), "+v"(W6));
            asm("v_permlane32_swap_b32 %0, %1" : "+v"(W5), "+v"(W7));
            pa2.u[0] = W0; pa2.u[1] = W1; pa2.u[2] = W2; pa2.u[3] = W3;
            pa3.u[0] = W4; pa3.u[1] = W5; pa3.u[2] = W6; pa3.u[3] = W7;
        }
        lsum += rs;

        // ---- PV(it): O^T[c][s] += V(32c x 16t) * P(16t x 32s), 8 cb x 4 ks ----
        __builtin_amdgcn_s_setprio(1);
        #pragma unroll
        for (int cb = 0; cb < 8; ++cb) {
            const int c = cb * 32 + l31;
            const unsigned short* Vr = &Vlds[cur][c * 64];
            const int f = l31 & 7;
            short8 vf0 = *reinterpret_cast<const short8*>(&Vr[((0 + h) ^ f) * 8]);
            short8 vf1 = *reinterpret_cast<const short8*>(&Vr[((2 + h) ^ f) * 8]);
            short8 vf2 = *reinterpret_cast<const short8*>(&Vr[((4 + h) ^ f) * 8]);
            short8 vf3 = *reinterpret_cast<const short8*>(&Vr[((6 + h) ^ f) * 8]);
            oacc[cb] = __builtin_amdgcn_mfma_f32_32x32x16_bf16(vf0, pa0.v, oacc[cb], 0, 0, 0);
            oacc[cb] = __builtin_amdgcn_mfma_f32_32x32x16_bf16(vf1, pa1.v, oacc[cb], 0, 0, 0);
            oacc[cb] = __builtin_amdgcn_mfma_f32_32x32x16_bf16(vf2, pa2.v, oacc[cb], 0, 0, 0);
            oacc[cb] = __builtin_amdgcn_mfma_f32_32x32x16_bf16(vf3, pa3.v, oacc[cb], 0, 0, 0);
        }
        __builtin_amdgcn_s_setprio(0);

        // drain this body's K(it+1)+V(it+1) DMAs -> next barrier guarantees them landed
        asm volatile("s_waitcnt vmcnt(0)" ::: "memory");
        __builtin_amdgcn_sched_barrier(0);
    }

    // ---- epilogue: reduce lsum across h, store partial O^T and l ----
    float lt = lsum + __shfl_xor(lsum, 32);          // full row sum for this t-chunk
    float* dst = (th == 0) ? part0 : (th == 1) ? part1 : (th == 2) ? part2 : part3;
    if (lane < 32) lbuf[th * 16384 + n * 4096 + s0 + lane] = lt;
    float* on = dst + (size_t)n * C_CH * S_LEN;
    #pragma unroll
    for (int cb = 0; cb < 8; ++cb) {
        #pragma unroll
        for (int r = 0; r < 16; ++r) {
            const int c = cb * 32 + (r & 3) + 8 * (r >> 2) + 4 * h;
            on[(size_t)c * S_LEN + s0 + l31] = oacc[cb][r];
        }
    }
}

// ---------- kernel 5: combine t-chunks: out = sum(p_i) / sum(l_i) ----------
template<int TSPLIT>
__global__ void nlm_combine_kernel(float* __restrict__ out, const float* __restrict__ p1,
                                   const float* __restrict__ p2, const float* __restrict__ p3,
                                   const float* __restrict__ lbuf) {
    const size_t e0 = ((size_t)blockIdx.x * 256 + threadIdx.x) * 4;
    const int n = (int)(e0 >> 20);
    const int s = (int)(e0 & 4095);
    float4 o = *reinterpret_cast<const float4*>(out + e0);
    float4 l = *reinterpret_cast<const float4*>(lbuf + n * 4096 + s);
    {
        float4 ov = *reinterpret_cast<const float4*>(p1 + e0);
        float4 lv = *reinterpret_cast<const float4*>(lbuf + 16384 + n * 4096 + s);
        o.x += ov.x; o.y += ov.y; o.z += ov.z; o.w += ov.w;
        l.x += lv.x; l.y += lv.y; l.z += lv.z; l.w += lv.w;
    }
    if (TSPLIT == 4) {
        float4 ov = *reinterpret_cast<const float4*>(p2 + e0);
        float4 lv = *reinterpret_cast<const float4*>(lbuf + 2 * 16384 + n * 4096 + s);
        o.x += ov.x; o.y += ov.y; o.z += ov.z; o.w += ov.w;
        l.x += lv.x; l.y += lv.y; l.z += lv.z; l.w += lv.w;
        float4 ow = *reinterpret_cast<const float4*>(p3 + e0);
        float4 lw = *reinterpret_cast<const float4*>(lbuf + 3 * 16384 + n * 4096 + s);
        o.x += ow.x; o.y += ow.y; o.z += ow.z; o.w += ow.w;
        l.x += lw.x; l.y += lw.y; l.z += lw.z; l.w += lw.w;
    }
    float4 r;
    r.x = o.x / l.x; r.y = o.y / l.y; r.z = o.z / l.z; r.w = o.w / l.w;
    *reinterpret_cast<float4*>(out + e0) = r;
}

extern "C" void kernel_launch(void* const* d_in, const int* in_sizes, int n_in,
                              void* d_out, int out_size, void* d_ws, size_t ws_size,
                              hipStream_t stream) {
    const float* x  = (const float*)d_in[0];
    const float* tw = (const float*)d_in[1];
    const float* tb = (const float*)d_in[2];
    const float* pw = (const float*)d_in[3];
    const float* pb = (const float*)d_in[4];
    float* out = (float*)d_out;

    char* ws = (char*)d_ws;
    unsigned short* xb = (unsigned short*)(ws);               //  8,388,608 B
    unsigned short* Qb = (unsigned short*)(ws + 8388608);     //  4,194,304 B
    unsigned short* Kb = (unsigned short*)(ws + 12582912);    //  4,194,304 B
    unsigned short* wb = (unsigned short*)(ws + 16777216);    //    131,072 B
    float*          lb = (float*)(ws + 16908288);             //    262,144 B
    float*          p1 = (float*)(ws + 17825792);             // 16,777,216 B
    float*          p2 = (float*)(ws + 34603008);             // 16,777,216 B
    float*          p3 = (float*)(ws + 51380224);             // 16,777,216 B

    nlm_conv_kernel<<<4096, 256, 0, stream>>>(x, xb);
    nlm_wconv_kernel<<<64, 256, 0, stream>>>(tw, pw, wb);
    nlm_proj_kernel<<<dim3(64, 4), 256, 0, stream>>>(x, wb, tb, pb, Qb, Kb);
    if (ws_size >= (size_t)68157440) {               // 4-way t-split: 256 blocks, 8 waves
        nlm_attn_kernel<4><<<256, 512, 0, stream>>>(Qb, Kb, xb, out, p1, p2, p3, lb);
        nlm_combine_kernel<4><<<4096, 256, 0, stream>>>(out, p1, p2, p3, lb);
    } else {                                          // fallback: 2-way t-split
        nlm_attn_kernel<2><<<128, 512, 0, stream>>>(Qb, Kb, xb, out, p1, p1, p1, lb);
        nlm_combine_kernel<2><<<4096, 256, 0, stream>>>(out, p1, p1, p1, lb);
    }
}

// Round 14
// 98.551 us; speedup vs baseline: 1.4496x; 1.0221x over previous
//
#include <hip/hip_runtime.h>

#define S_LEN 4096   // H*W
#define C_CH  256
#define D_CH  128
// softmax scale for exp2: lambda = (1/sqrt(256)) * log2(e)  [applied at exp2, NOT folded
// into Q: fp8 e4m3 min-normal is 2^-6, lambda*q ~0.014 would hit denormals]
#define LAMBDA 0.09016844005555896f

typedef __attribute__((ext_vector_type(8)))  short short8;   // 8 x bf16 (4 VGPR)
typedef __attribute__((ext_vector_type(4)))  float f32x4;
typedef __attribute__((ext_vector_type(16))) float f32x16;

union PFrag { unsigned u[4]; short8 v; };

static __device__ __forceinline__ unsigned short f2bf(float x) {
    union { float f; unsigned u; } v; v.f = x;
    unsigned r = v.u + 0x7FFFu + ((v.u >> 16) & 1u);   // RNE
    return (unsigned short)(r >> 16);
}

static __device__ __forceinline__ void gload_lds16(const void* g, void* l) {
    __builtin_amdgcn_global_load_lds(
        (const __attribute__((address_space(1))) void*)g,
        (__attribute__((address_space(3))) void*)l, 16, 0, 0);
}

// ---------- kernel 1: x f32 -> xb bf16, layout [n][c][s] (V operand) ----------
__global__ void nlm_conv_kernel(const float* __restrict__ x, unsigned short* __restrict__ xb) {
    size_t base = ((size_t)blockIdx.x * 256 + threadIdx.x) * 4;
    float4 v = *reinterpret_cast<const float4*>(x + base);
    ushort4 b; b.x = f2bf(v.x); b.y = f2bf(v.y); b.z = f2bf(v.z); b.w = f2bf(v.w);
    *reinterpret_cast<ushort4*>(xb + base) = b;
}

// ---------- kernel 2: theta_w/phi_w f32 -> bf16, wb = [2][128][256] ----------
__global__ void nlm_wconv_kernel(const float* __restrict__ tw, const float* __restrict__ pw,
                                 unsigned short* __restrict__ wb) {
    int base = (blockIdx.x * 256 + threadIdx.x) * 4;
    const float* src = (base < 32768) ? (tw + base) : (pw + base - 32768);
    float4 v = *reinterpret_cast<const float4*>(src);
    ushort4 b; b.x = f2bf(v.x); b.y = f2bf(v.y); b.z = f2bf(v.z); b.w = f2bf(v.w);
    *reinterpret_cast<ushort4*>(wb + base) = b;
}

// ---------- kernel 3: projections Q[n][s][128], K[n][t][128] as fp8 e4m3 ----------
__launch_bounds__(256, 1)
__global__ void nlm_proj_kernel(const float* __restrict__ x,
                                const unsigned short* __restrict__ wb,
                                const float* __restrict__ tb, const float* __restrict__ pbias,
                                unsigned char* __restrict__ Qb8, unsigned char* __restrict__ Kb8) {
    const int n    = blockIdx.y;
    const int wave = threadIdx.x >> 6;
    const int lane = threadIdx.x & 63;
    const int sl   = lane & 15, g = lane >> 4;
    const int s0   = blockIdx.x * 64 + wave * 16;
    const float* xn = x + (size_t)n * C_CH * S_LEN;

    f32x4 acc[16];
    #pragma unroll
    for (int i = 0; i < 16; ++i) acc[i] = (f32x4){0.f, 0.f, 0.f, 0.f};

    #pragma unroll 1
    for (int cc = 0; cc < 8; ++cc) {
        short8 af;                                   // A[m=s][k=c]: lane m=sl, k=g*8+j
        #pragma unroll
        for (int j = 0; j < 8; ++j) {
            float v = xn[(size_t)(cc * 32 + g * 8 + j) * S_LEN + s0 + sl];
            af[j] = (short)f2bf(v);
        }
        #pragma unroll
        for (int t = 0; t < 16; ++t) {               // 0..7 theta tiles, 8..15 phi tiles
            const unsigned short* wp = wb + (size_t)(t >> 3) * (D_CH * C_CH)
                                          + (size_t)((t & 7) * 16 + sl) * C_CH + cc * 32 + g * 8;
            short8 bf = *reinterpret_cast<const short8*>(wp);
            acc[t] = __builtin_amdgcn_mfma_f32_16x16x32_bf16(af, bf, acc[t], 0, 0, 0);
        }
    }
    #pragma unroll
    for (int t = 0; t < 16; ++t) {
        const float bias = (t < 8 ? tb : pbias)[(t & 7) * 16 + sl];
        unsigned char* dst = (t < 8 ? Qb8 : Kb8) + (size_t)n * S_LEN * D_CH;
        const int col = (t & 7) * 16 + sl;
        float v0 = acc[t][0] + bias, v1 = acc[t][1] + bias;
        float v2 = acc[t][2] + bias, v3 = acc[t][3] + bias;
        unsigned u01, u23;                           // 2 fp8 in low 16 bits each (RNE, sat)
        asm("v_cvt_pk_fp8_f32 %0, %1, %2" : "=v"(u01) : "v"(v0), "v"(v1));
        asm("v_cvt_pk_fp8_f32 %0, %1, %2" : "=v"(u23) : "v"(v2), "v"(v3));
        dst[(size_t)(s0 + g * 4 + 0) * D_CH + col] = (unsigned char)(u01 & 0xff);
        dst[(size_t)(s0 + g * 4 + 1) * D_CH + col] = (unsigned char)((u01 >> 8) & 0xff);
        dst[(size_t)(s0 + g * 4 + 2) * D_CH + col] = (unsigned char)(u23 & 0xff);
        dst[(size_t)(s0 + g * 4 + 3) * D_CH + col] = (unsigned char)((u23 >> 8) & 0xff);
    }
}

// ---------- kernel 4: flash attention, 8-wave blocks, BT=64, fp8 QK, t-split ----------
// 64*TSPLIT blocks (TSPLIT=4 -> 256 = 1/CU, 2 waves/SIMD). Block = 8 waves x 32 q-rows
// = 256 s; BT=64 (16 bodies). QK in fp8 e4m3 (mfma_32x32x16_fp8_fp8, 8B frags, b64
// LDS reads = free 2-way); PV in bf16. Per body: ONE barrier; stage (1 K + 4 V insts
// per wave); QK 2 chains of 8; exp(S*lambda); cvt_pk+permlane -> 4 P-frags; PV 32 MFMA;
// vmcnt(0). K 2-buf (8KB/slot) + V 2-buf (32KB/slot) = 80 KB LDS.
template<int TSPLIT>
__launch_bounds__(512, 2)
__global__ void nlm_attn_kernel(const unsigned char* __restrict__ Qb8,
                                const unsigned char* __restrict__ Kb8,
                                const unsigned short* __restrict__ xb,
                                float* __restrict__ part0, float* __restrict__ part1,
                                float* __restrict__ part2, float* __restrict__ part3,
                                float* __restrict__ lbuf) {
    constexpr int TRANGE = S_LEN / TSPLIT;
    constexpr int NITv   = TRANGE / 64;
    constexpr int TOTAL  = 64 * TSPLIT;
    // XCD swizzle: TOTAL/8 consecutive newb per XCD.
    const int sid  = blockIdx.x;
    const int newb = (sid & 7) * (TOTAL / 8) + (sid >> 3);
    const int n    = newb / (16 * TSPLIT);
    const int th   = (newb >> 4) & (TSPLIT - 1);
    const int sb   = newb & 15;
    const int lane = threadIdx.x & 63;
    const int wave = threadIdx.x >> 6;               // 0..7
    const int l31  = lane & 31;
    const int h    = lane >> 5;
    const int s0   = sb * 256 + wave * 32;           // this wave's 32 q-rows
    const int tbase = th * TRANGE;

    __shared__ unsigned char  Klds[2][64 * 128];     // fp8 [t-local][d], chunk-XOR swizzled
    __shared__ unsigned short Vlds[2][256 * 64];     // bf16 [c][t-local], chunk-XOR swizzled

    const unsigned char* Qn8 = Qb8 + (size_t)n * S_LEN * D_CH;
    const unsigned char* Kn8 = Kb8 + (size_t)n * S_LEN * D_CH;
    const unsigned short* xn = xb + (size_t)n * C_CH * S_LEN;

    // Q fragments (B operand, fp8): lane (s=l31, h): d-bytes = ks*16 + h*8 + j
    long qf8[8];
    #pragma unroll
    for (int ks = 0; ks < 8; ++ks)
        qf8[ks] = *reinterpret_cast<const long*>(Qn8 + (size_t)(s0 + l31) * D_CH + ks * 16 + h * 8);

    f32x16 oacc[8];                                  // O^T: c-block cb*32.., s = s0+l31
    #pragma unroll
    for (int i = 0; i < 8; ++i)
        #pragma unroll
        for (int r = 0; r < 16; ++r) oacc[i][r] = 0.f;
    float lsum = 0.f;                                // per-lane partial row sum

    auto kstage = [&](int itv, int slot) {           // 64 rows x 128B fp8, 1 inst/wave
        const int it = itv < NITv ? itv : NITv - 1;  // clamp: tail stages dup tile (unread)
        const int t0 = tbase + it * 64;
        const int rl = wave * 8 + (lane >> 3);
        const int ch = (lane & 7) ^ (rl & 7);        // LDS[r][q] = G[t0+r][q^(r&7)]
        gload_lds16(Kn8 + (size_t)(t0 + rl) * D_CH + ch * 16,
                    &Klds[slot][wave * 8 * 128]);
    };
    auto vstage = [&](int itv, int slot) {           // 256 rows x 128B bf16, 4 insts/wave
        const int it = itv < NITv ? itv : NITv - 1;
        const int t0 = tbase + it * 64;
        #pragma unroll
        for (int i = 0; i < 4; ++i) {
            const int row = wave * 32 + i * 8 + (lane >> 3);
            const int ch = (lane & 7) ^ (row & 7);   // LDS[c][q] = G[c][q^(c&7)]
            gload_lds16(xn + (size_t)row * S_LEN + t0 + ch * 8,
                        &Vlds[slot][(wave * 32 + i * 8) * 64]);
        }
    };

    // prologue: K(0), V(0)
    kstage(0, 0); vstage(0, 0);
    asm volatile("s_waitcnt vmcnt(0)" ::: "memory");

    #pragma unroll 1
    for (int it = 0; it < NITv; ++it) {
        const int cur = it & 1;
        __builtin_amdgcn_s_barrier();                // K(it),V(it) landed; buf cur^1 free
        __builtin_amdgcn_sched_barrier(0);
        kstage(it + 1, cur ^ 1);
        vstage(it + 1, cur ^ 1);

        // ---- QK(it): S^T = K_tile(64t x 128d) * Q^T(128d x 32s), fp8, 2 chains ----
        f32x16 sa, sb2;                              // t 0..31 / t 32..63
        #pragma unroll
        for (int r = 0; r < 16; ++r) { sa[r] = 0.f; sb2[r] = 0.f; }
        const int f = l31 & 7;
        __builtin_amdgcn_s_setprio(1);
        #pragma unroll
        for (int ks = 0; ks < 8; ++ks) {             // A: lane (t,h): d-bytes=ks*16+h*8+j
            const int co = ((ks ^ f) * 16) + h * 8;
            long kflo = *reinterpret_cast<const long*>(&Klds[cur][l31 * 128 + co]);
            long kfhi = *reinterpret_cast<const long*>(&Klds[cur][(32 + l31) * 128 + co]);
            sa  = __builtin_amdgcn_mfma_f32_32x32x16_fp8_fp8(kflo, qf8[ks], sa,  0, 0, 0);
            sb2 = __builtin_amdgcn_mfma_f32_32x32x16_fp8_fp8(kfhi, qf8[ks], sb2, 0, 0, 0);
        }
        __builtin_amdgcn_s_setprio(0);

        // ---- exp(S*lambda) (no max) + P-frags (cvt_pk + permlane32_swap) ----
        PFrag pa0, pa1, pa2, pa3;
        float rs = 0.f;
        {
            float p[16];
            #pragma unroll
            for (int r = 0; r < 16; ++r) { p[r] = __builtin_amdgcn_exp2f(sa[r] * LAMBDA); rs += p[r]; }
            unsigned W0, W1, W2, W3, W4, W5, W6, W7;
            asm("v_cvt_pk_bf16_f32 %0, %1, %2" : "=v"(W0) : "v"(p[0]),  "v"(p[1]));
            asm("v_cvt_pk_bf16_f32 %0, %1, %2" : "=v"(W1) : "v"(p[2]),  "v"(p[3]));
            asm("v_cvt_pk_bf16_f32 %0, %1, %2" : "=v"(W2) : "v"(p[4]),  "v"(p[5]));
            asm("v_cvt_pk_bf16_f32 %0, %1, %2" : "=v"(W3) : "v"(p[6]),  "v"(p[7]));
            asm("v_cvt_pk_bf16_f32 %0, %1, %2" : "=v"(W4) : "v"(p[8]),  "v"(p[9]));
            asm("v_cvt_pk_bf16_f32 %0, %1, %2" : "=v"(W5) : "v"(p[10]), "v"(p[11]));
            asm("v_cvt_pk_bf16_f32 %0, %1, %2" : "=v"(W6) : "v"(p[12]), "v"(p[13]));
            asm("v_cvt_pk_bf16_f32 %0, %1, %2" : "=v"(W7) : "v"(p[14]), "v"(p[15]));
            asm("v_permlane32_swap_b32 %0, %1" : "+v"(W0), "+v"(W2));
            asm("v_permlane32_swap_b32 %0, %1" : "+v"(W1), "+v"(W3));
            asm("v_permlane32_swap_b32 %0, %1" : "+v"(W4), "+v"(W6));
            asm("v_permlane32_swap_b32 %0, %1" : "+v"(W5), "+v"(W7));
            pa0.u[0] = W0; pa0.u[1] = W1; pa0.u[2] = W2; pa0.u[3] = W3;
            pa1.u[0] = W4; pa1.u[1] = W5; pa1.u[2] = W6; pa1.u[3] = W7;
        }
        {
            float p[16];
            #pragma unroll
            for (int r = 0; r < 16; ++r) { p[r] = __builtin_amdgcn_exp2f(sb2[r] * LAMBDA); rs += p[r]; }
            unsigned W0, W1, W2, W3, W4, W5, W6, W7;
            asm("v_cvt_pk_bf16_f32 %0, %1, %2" : "=v"(W0) : "v"(p[0]),  "v"(p[1]));
            asm("v_cvt_pk_bf16_f32 %0, %1, %2" : "=v"(W1) : "v"(p[2]),  "v"(p[3]));
            asm("v_cvt_pk_bf16_f32 %0, %1, %2" : "=v"(W2) : "v"(p[4]),  "v"(p[5]));
            asm("v_cvt_pk_bf16_f32 %0, %1, %2" : "=v"(W3) : "v"(p[6]),  "v"(p[7]));
            asm("v_cvt_pk_bf16_f32 %0, %1, %2" : "=v"(W4) : "v"(p[8]),  "v"(p[9]));
            asm("v_cvt_pk_bf16_f32 %0, %1, %2" : "=v"(W5) : "v"(p[10]), "v"(p[11]));
            asm("v_cvt_pk_bf16_f32 %0, %1, %2" : "=v"(W6) : "v"(p[12]), "v"(p[13]));
            asm("v_cvt_pk_bf16_f32 %0, %1, %2" : "=v"(W7) : "v"(p[14]), "v"(p[15]));
            asm("v_permlane32_swap_b32 %0, %1" : "+v"(W0), "+v"(W2));
            asm("v_permlane32_swap_b32 %0, %1" : "+v"(W1), "+v"(W3));
            asm("v_permlane32_swap_b32 %0, %1" : "+v"(W4), "+v"(W6));
            asm("v_permlane32_swap_b32 %0, %1" : "+v"(W5), "+v"(W7));
            pa2.u[0] = W0; pa2.u[1] = W1; pa2.u[2] = W2; pa2.u[3] = W3;
            pa3.u[0] = W4; pa3.u[1] = W5; pa3.u[2] = W6; pa3.u[3] = W7;
        }
        lsum += rs;

        // ---- PV(it): O^T[c][s] += V(32c x 16t) * P(16t x 32s), bf16, 8 cb x 4 ks ----
        __builtin_amdgcn_s_setprio(1);
        #pragma unroll
        for (int cb = 0; cb < 8; ++cb) {
            const int c = cb * 32 + l31;
            const unsigned short* Vr = &Vlds[cur][c * 64];
            const int fv = l31 & 7;
            short8 vf0 = *reinterpret_cast<const short8*>(&Vr[((0 + h) ^ fv) * 8]);
            short8 vf1 = *reinterpret_cast<const short8*>(&Vr[((2 + h) ^ fv) * 8]);
            short8 vf2 = *reinterpret_cast<const short8*>(&Vr[((4 + h) ^ fv) * 8]);
            short8 vf3 = *reinterpret_cast<const short8*>(&Vr[((6 + h) ^ fv) * 8]);
            oacc[cb] = __builtin_amdgcn_mfma_f32_32x32x16_bf16(vf0, pa0.v, oacc[cb], 0, 0, 0);
            oacc[cb] = __builtin_amdgcn_mfma_f32_32x32x16_bf16(vf1, pa1.v, oacc[cb], 0, 0, 0);
            oacc[cb] = __builtin_amdgcn_mfma_f32_32x32x16_bf16(vf2, pa2.v, oacc[cb], 0, 0, 0);
            oacc[cb] = __builtin_amdgcn_mfma_f32_32x32x16_bf16(vf3, pa3.v, oacc[cb], 0, 0, 0);
        }
        __builtin_amdgcn_s_setprio(0);

        // drain this body's K(it+1)+V(it+1) DMAs -> next barrier guarantees them landed
        asm volatile("s_waitcnt vmcnt(0)" ::: "memory");
        __builtin_amdgcn_sched_barrier(0);
    }

    // ---- epilogue: reduce lsum across h, store partial O^T and l ----
    float lt = lsum + __shfl_xor(lsum, 32);          // full row sum for this t-chunk
    float* dst = (th == 0) ? part0 : (th == 1) ? part1 : (th == 2) ? part2 : part3;
    if (lane < 32) lbuf[th * 16384 + n * 4096 + s0 + lane] = lt;
    float* on = dst + (size_t)n * C_CH * S_LEN;
    #pragma unroll
    for (int cb = 0; cb < 8; ++cb) {
        #pragma unroll
        for (int r = 0; r < 16; ++r) {
            const int c = cb * 32 + (r & 3) + 8 * (r >> 2) + 4 * h;
            on[(size_t)c * S_LEN + s0 + l31] = oacc[cb][r];
        }
    }
}

// ---------- kernel 5: combine t-chunks: out = sum(p_i) / sum(l_i) ----------
template<int TSPLIT>
__global__ void nlm_combine_kernel(float* __restrict__ out, const float* __restrict__ p1,
                                   const float* __restrict__ p2, const float* __restrict__ p3,
                                   const float* __restrict__ lbuf) {
    const size_t e0 = ((size_t)blockIdx.x * 256 + threadIdx.x) * 4;
    const int n = (int)(e0 >> 20);
    const int s = (int)(e0 & 4095);
    float4 o = *reinterpret_cast<const float4*>(out + e0);
    float4 l = *reinterpret_cast<const float4*>(lbuf + n * 4096 + s);
    {
        float4 ov = *reinterpret_cast<const float4*>(p1 + e0);
        float4 lv = *reinterpret_cast<const float4*>(lbuf + 16384 + n * 4096 + s);
        o.x += ov.x; o.y += ov.y; o.z += ov.z; o.w += ov.w;
        l.x += lv.x; l.y += lv.y; l.z += lv.z; l.w += lv.w;
    }
    if (TSPLIT == 4) {
        float4 ov = *reinterpret_cast<const float4*>(p2 + e0);
        float4 lv = *reinterpret_cast<const float4*>(lbuf + 2 * 16384 + n * 4096 + s);
        o.x += ov.x; o.y += ov.y; o.z += ov.z; o.w += ov.w;
        l.x += lv.x; l.y += lv.y; l.z += lv.z; l.w += lv.w;
        float4 ow = *reinterpret_cast<const float4*>(p3 + e0);
        float4 lw = *reinterpret_cast<const float4*>(lbuf + 3 * 16384 + n * 4096 + s);
        o.x += ow.x; o.y += ow.y; o.z += ow.z; o.w += ow.w;
        l.x += lw.x; l.y += lw.y; l.z += lw.z; l.w += lw.w;
    }
    float4 r;
    r.x = o.x / l.x; r.y = o.y / l.y; r.z = o.z / l.z; r.w = o.w / l.w;
    *reinterpret_cast<float4*>(out + e0) = r;
}

extern "C" void kernel_launch(void* const* d_in, const int* in_sizes, int n_in,
                              void* d_out, int out_size, void* d_ws, size_t ws_size,
                              hipStream_t stream) {
    const float* x  = (const float*)d_in[0];
    const float* tw = (const float*)d_in[1];
    const float* tb = (const float*)d_in[2];
    const float* pw = (const float*)d_in[3];
    const float* pb = (const float*)d_in[4];
    float* out = (float*)d_out;

    char* ws = (char*)d_ws;
    unsigned short* xb = (unsigned short*)(ws);               //  8,388,608 B
    unsigned char*  Qb8 = (unsigned char*)(ws + 8388608);     //  2,097,152 B (fp8)
    unsigned char*  Kb8 = (unsigned char*)(ws + 12582912);    //  2,097,152 B (fp8)
    unsigned short* wb = (unsigned short*)(ws + 16777216);    //    131,072 B
    float*          lb = (float*)(ws + 16908288);             //    262,144 B
    float*          p1 = (float*)(ws + 17825792);             // 16,777,216 B
    float*          p2 = (float*)(ws + 34603008);             // 16,777,216 B
    float*          p3 = (float*)(ws + 51380224);             // 16,777,216 B

    nlm_conv_kernel<<<4096, 256, 0, stream>>>(x, xb);
    nlm_wconv_kernel<<<64, 256, 0, stream>>>(tw, pw, wb);
    nlm_proj_kernel<<<dim3(64, 4), 256, 0, stream>>>(x, wb, tb, pb, Qb8, Kb8);
    if (ws_size >= (size_t)68157440) {               // 4-way t-split: 256 blocks, 8 waves
        nlm_attn_kernel<4><<<256, 512, 0, stream>>>(Qb8, Kb8, xb, out, p1, p2, p3, lb);
        nlm_combine_kernel<4><<<4096, 256, 0, stream>>>(out, p1, p2, p3, lb);
    } else {                                          // fallback: 2-way t-split
        nlm_attn_kernel<2><<<128, 512, 0, stream>>>(Qb8, Kb8, xb, out, p1, p1, p1, lb);
        nlm_combine_kernel<2><<<4096, 256, 0, stream>>>(out, p1, p1, p1, lb);
    }
}